// Round 8
// baseline (7625.629 us; speedup 1.0000x reference)
//
#include <hip/hip_runtime.h>
#include <hip/hip_bf16.h>

#define Bdim 128
#define Tdim 256
#define DIN 512
#define Hdim 1024
#define Sdim 128
#define DHdim 1024
#define KG 1152   // S + H (gates GEMM K)
#define KP 1536   // DIN + H (heads GEMM K)
#define NBLK 192  // persistent: 128 gates blocks + 64 heads blocks

using short8  = __attribute__((ext_vector_type(8))) short;   // 8 bf16 (4 VGPRs)
using floatx4 = __attribute__((ext_vector_type(4))) float;   // MFMA accum
typedef unsigned long long ull;

#define MFMA(a, b, c) __builtin_amdgcn_mfma_f32_16x16x32_bf16((a), (b), (c), 0, 0, 0)

// ---- workspace layout (bytes). Scan-phase staging (xbf/Wg/Wmv) unions with
// Hbuf (decoder intermediate), which is written only after the scan finishes.
#define XBF_OFF   0ull            // 128*256*512 bf16 = 33,554,432
#define WG_OFF    33554432ull     // 4096*1152 bf16 = 9,437,184
#define WMV_OFF   42991616ull     // 256*1536 bf16 = 786,432
#define HB_OFF    0ull            // 32768*1024 bf16 = 67,108,864 (unions scan staging)
#define WD1_OFF   67108864ull     // 1024*128 bf16 = 262,144
#define WD2_OFF   67371008ull     // 512*1024 bf16 = 1,048,576
#define AB_OFF    68419584ull     // 2 x 128*1152 bf16 (ping-pong [z|h]) = 589,824
#define AB_SZ     294912ull
#define ZALL_OFF  69009408ull     // 32768*128 bf16 = 8,388,608
#define KL_OFF    77398016ull     // 1 f32
#define FLG_OFF   77398144ull     // 192 x u32 monotonic per-producer seqno flags

__device__ __forceinline__ float sigf(float v) { return 1.0f / (1.0f + __expf(-v)); }
__device__ __forceinline__ float tanhfast(float v) { return 1.0f - 2.0f / (__expf(2.0f * v) + 1.0f); }

// Round-8: consumer side switches from sc0sc1 LLC-direct loads (measured hard
// cap ~0.8 TB/s on the L2-bypass request path across r0/r2/r3/r7) to
// ACQUIRE-FENCE + PLAIN loads: the agent acquire fence invalidates stale
// L1/L2 lines; plain loads then refill from LLC once per XCD and the 64x
// amplified re-reads become L2 hits (~34 TB/s aggregate).
#define AFENCE() __builtin_amdgcn_fence(__ATOMIC_ACQUIRE, "agent")

__device__ __forceinline__ void astore8(__hip_bfloat16* p, ull v) {
  __hip_atomic_store((ull*)(void*)p, v, __ATOMIC_RELAXED, __HIP_MEMORY_SCOPE_AGENT);
}

// Wave0-only polling + s_sleep(8) backoff (round-3 proven); callers release the
// other waves with __syncthreads().
__device__ __forceinline__ void waitflags(unsigned* flags, int base, int mask,
                                          unsigned target, int lane) {
  unsigned* p = flags + base + (lane & mask);
  while (!__all((int)(__hip_atomic_load(p, __ATOMIC_RELAXED, __HIP_MEMORY_SCOPE_AGENT) >= target))) {
    __builtin_amdgcn_s_sleep(8);
  }
}

// ---------------- prep: fp32->bf16 conversions, weight packing, state zeroing
__global__ __launch_bounds__(256) void prep_kernel(
    const float* __restrict__ x, const float* __restrict__ W_ih,
    const float* __restrict__ W_hh, const float* __restrict__ Wm,
    const float* __restrict__ Wv, const float* __restrict__ Wd1,
    const float* __restrict__ Wd2, char* __restrict__ ws) {
  long long i = (long long)blockIdx.x * 256 + threadIdx.x;
  if (i < 16777216LL) {  // x -> xbf  [B][T][DIN]
    ((__hip_bfloat16*)(ws + XBF_OFF))[i] = __float2bfloat16(x[i]);
    return;
  }
  i -= 16777216LL;
  if (i < 4718592LL) {  // Wg[4096][1152] = [W_ih | W_hh]
    int j = (int)(i / KG), k = (int)(i % KG);
    float v = (k < Sdim) ? W_ih[j * Sdim + k] : W_hh[(long long)j * Hdim + (k - Sdim)];
    ((__hip_bfloat16*)(ws + WG_OFF))[i] = __float2bfloat16(v);
    return;
  }
  i -= 4718592LL;
  if (i < 393216LL) {  // Wmv[256][1536] = [Wm ; Wv]
    int r = (int)(i / KP), k = (int)(i % KP);
    float v = (r < Sdim) ? Wm[r * KP + k] : Wv[(r - Sdim) * KP + k];
    ((__hip_bfloat16*)(ws + WMV_OFF))[i] = __float2bfloat16(v);
    return;
  }
  i -= 393216LL;
  if (i < 131072LL) { ((__hip_bfloat16*)(ws + WD1_OFF))[i] = __float2bfloat16(Wd1[i]); return; }
  i -= 131072LL;
  if (i < 524288LL) { ((__hip_bfloat16*)(ws + WD2_OFF))[i] = __float2bfloat16(Wd2[i]); return; }
  i -= 524288LL;
  if (i < 147456LL) { ((__hip_bfloat16*)(ws + AB_OFF))[i] = __float2bfloat16(0.0f); return; }  // [z0|h0]=0
  i -= 147456LL;
  if (i == 0) { *((float*)(ws + KL_OFF)) = 0.0f; return; }
  i -= 1;
  if (i < 192LL) { ((unsigned*)(ws + FLG_OFF))[i] = 0u; return; }
}

// ---------------- persistent scan: whole T=256 recurrence in ONE kernel.
// Round-3 proven structure (192 blocks, 152-VGPR GEMM shape, wave0 poll,
// 8B packed h/z stores). Round-8 diff: A-matrix reads are acquire-fence +
// plain vectorized loads (L2-mediated) instead of sc0sc1 LLC-direct.
__global__ __launch_bounds__(256, 1) void scan_kernel(
    char* __restrict__ ws, const float* __restrict__ noise,
    const float* __restrict__ b_ih, const float* __restrict__ b_hh,
    const float* __restrict__ bm, const float* __restrict__ bv) {
  const __hip_bfloat16* WG = (const __hip_bfloat16*)(ws + WG_OFF);
  const __hip_bfloat16* WMV = (const __hip_bfloat16*)(ws + WMV_OFF);
  const __hip_bfloat16* xbf = (const __hip_bfloat16*)(ws + XBF_OFF);
  __hip_bfloat16* zall = (__hip_bfloat16*)(ws + ZALL_OFF);
  float* klacc = (float*)(ws + KL_OFF);
  unsigned* flags = (unsigned*)(ws + FLG_OFF);

  __shared__ float smem[8 * 256];  // heads cross-wave reduction only

  const int tid = threadIdx.x;
  const int lane = tid & 63;
  const int w = tid >> 6;
  const int row16 = lane & 15;
  const int quad = lane >> 4;
  const bool is_gates = (blockIdx.x < 128);

  // ---- gates-role setup
  const __hip_bfloat16* gb_bp[4];
  float biasv[4];
  int mhalf = 0, ngrp = 0;
  float creg[4] = {0.f, 0.f, 0.f, 0.f};
  // ---- heads-role setup
  const __hip_bfloat16* hd_bpm = nullptr;
  const __hip_bfloat16* hd_bpv = nullptr;
  int hd_mb = 0, hd_sb = 0, hd_nx = 0, hd_kbase = 0;
  float hbm = 0.f, hbv = 0.f;
  float klw = 0.f;  // heads w0: KL accumulated over all t

  if (is_gates) {
    mhalf = blockIdx.x >> 6;
    ngrp = blockIdx.x & 63;
    #pragma unroll
    for (int j = 0; j < 4; j++) {
      int idx = j * Hdim + ngrp * 16 + row16;  // gate j, hcol = ngrp*16+row16
      gb_bp[j] = WG + (size_t)idx * KG;
      biasv[j] = b_ih[idx] + b_hh[idx];
    }
  } else {
    int hb = blockIdx.x - 128;
    hd_mb = hb >> 3;
    hd_sb = hb & 7;
    int s = hd_sb * 16 + row16;
    hd_bpm = WMV + (size_t)s * KP;
    hd_bpv = WMV + (size_t)(128 + s) * KP;
    hbm = bm[s];
    hbv = bv[s];
    hd_kbase = w * 384;
    hd_nx = (hd_kbase < DIN) ? ((DIN - hd_kbase) >> 5) : 0;  // 12,4,0,0
    if (hd_nx > 12) hd_nx = 12;
  }

  for (int t = 0; t < Tdim; t++) {
    const int par = t & 1;
    const __hip_bfloat16* Ab = (const __hip_bfloat16*)(ws + AB_OFF + (ull)par * AB_SZ);
    __hip_bfloat16* AbW = (__hip_bfloat16*)(ws + AB_OFF + (ull)(par ^ 1) * AB_SZ);

    if (is_gates) {
      const __hip_bfloat16* aptr = Ab + (size_t)(mhalf * 64 + w * 16 + row16) * KG;
      floatx4 acc[4];
      #pragma unroll
      for (int j = 0; j < 4; j++)
        acc[j] = (floatx4){biasv[j], biasv[j], biasv[j], biasv[j]};

      // --- h-region first (K=128..1152): producers are same-mhalf gates (t)
      if (w == 0) waitflags(flags, mhalf * 64, 63, (unsigned)t, lane);
      __syncthreads();  // release: data ordered after wave0's flag observation
      AFENCE();         // invalidate stale L1/L2 lines; fills below come from LLC
      short8 areg[32];
      #pragma unroll
      for (int kt = 0; kt < 32; kt++)
        areg[kt] = *(const short8*)(aptr + Sdim + kt * 32 + quad * 8);
      #pragma unroll
      for (int kt = 0; kt < 32; kt++) {
        int k0 = Sdim + kt * 32 + quad * 8;
        #pragma unroll
        for (int j = 0; j < 4; j++)
          acc[j] = MFMA(areg[kt], *(const short8*)(gb_bp[j] + k0), acc[j]);
      }
      // --- z-region (K=0..128): producers are heads blocks for my rows (t)
      if (w == 0) waitflags(flags, 128 + mhalf * 32, 31, (unsigned)t, lane);
      __syncthreads();
      AFENCE();
      short8 zreg[4];
      #pragma unroll
      for (int kt = 0; kt < 4; kt++)
        zreg[kt] = *(const short8*)(aptr + kt * 32 + quad * 8);
      #pragma unroll
      for (int kt = 0; kt < 4; kt++) {
        int k0 = kt * 32 + quad * 8;
        #pragma unroll
        for (int j = 0; j < 4; j++)
          acc[j] = MFMA(zreg[kt], *(const short8*)(gb_bp[j] + k0), acc[j]);
      }
      // --- LSTM cell, fully lane-local: acc[j][r] = gate j at (row quad*4+r, hcol row16)
      int hc = ngrp * 16 + row16;
      #pragma unroll
      for (int r = 0; r < 4; r++) {
        float cn = sigf(acc[1][r]) * creg[r] + sigf(acc[0][r]) * tanhfast(acc[2][r]);
        creg[r] = cn;
        float hn = sigf(acc[3][r]) * tanhfast(cn);
        __hip_bfloat16 hbf = __float2bfloat16(hn);
        unsigned hu = (unsigned)reinterpret_cast<unsigned short&>(hbf);
        unsigned up = hu | (__shfl_xor(hu, 1, 64) << 16);  // hcols {hc, hc+1}
        unsigned uq = __shfl_xor(up, 2, 64);               // hcols {hc+2, hc+3}
        if ((row16 & 3) == 0) {
          int grow = mhalf * 64 + w * 16 + quad * 4 + r;
          astore8(AbW + (size_t)grow * KG + Sdim + hc, (ull)up | ((ull)uq << 32));
        }
      }
      __syncthreads();  // drain all waves' h-stores (vmcnt 0) before publishing
      if (tid == 0)
        __hip_atomic_store(&flags[blockIdx.x], (unsigned)(t + 1),
                           __ATOMIC_RELAXED, __HIP_MEMORY_SCOPE_AGENT);
    } else {
      // --- noise prefetch (static input): issue before any wait, used in epilogue
      float nz[4];
      if (w == 0) {
        #pragma unroll
        for (int r = 0; r < 4; r++) {
          int b = hd_mb * 16 + quad * 4 + r;
          int s = hd_sb * 16 + row16;
          nz[r] = noise[((size_t)b * Tdim + t) * Sdim + s];
        }
      }
      // --- x-region first (static input, no wait)
      const __hip_bfloat16* axp = xbf + ((size_t)(hd_mb * 16 + row16) * Tdim + t) * DIN;
      const __hip_bfloat16* ahp = AbW + (size_t)(hd_mb * 16 + row16) * KG + Sdim;
      floatx4 am, av;
      if (w == 0) { am = (floatx4){hbm, hbm, hbm, hbm}; av = (floatx4){hbv, hbv, hbv, hbv}; }
      else        { am = (floatx4){0.f, 0.f, 0.f, 0.f}; av = (floatx4){0.f, 0.f, 0.f, 0.f}; }
      #pragma unroll
      for (int kt = 0; kt < 12; kt++) {
        if (kt < hd_nx) {
          int k0 = hd_kbase + kt * 32 + quad * 8;
          short8 a = *(const short8*)(axp + k0);
          am = MFMA(a, *(const short8*)(hd_bpm + k0), am);
          av = MFMA(a, *(const short8*)(hd_bpv + k0), av);
        }
      }
      // --- h-region: wait for the 64 gates blocks covering my rows to finish step t
      if (w == 0) waitflags(flags, (hd_mb >> 2) * 64, 63, (unsigned)(t + 1), lane);
      __syncthreads();
      AFENCE();
      short8 hreg[12];
      #pragma unroll
      for (int kt = 0; kt < 12; kt++) {
        if (kt >= hd_nx)
          hreg[kt] = *(const short8*)(ahp + hd_kbase + kt * 32 + quad * 8 - DIN);
      }
      #pragma unroll
      for (int kt = 0; kt < 12; kt++) {
        if (kt >= hd_nx) {
          int k0 = hd_kbase + kt * 32 + quad * 8;
          am = MFMA(hreg[kt], *(const short8*)(hd_bpm + k0), am);
          av = MFMA(hreg[kt], *(const short8*)(hd_bpv + k0), av);
        }
      }
      // --- cross-wave K reduction through LDS
      #pragma unroll
      for (int r = 0; r < 4; r++) {
        smem[(w * 2 + 0) * 256 + lane * 4 + r] = am[r];
        smem[(w * 2 + 1) * 256 + lane * 4 + r] = av[r];
      }
      __syncthreads();
      if (w == 0) {
        #pragma unroll
        for (int r = 0; r < 4; r++) {
          int idx = lane * 4 + r;
          float mean = smem[0 * 256 + idx] + smem[2 * 256 + idx] +
                       smem[4 * 256 + idx] + smem[6 * 256 + idx];
          float lv = smem[1 * 256 + idx] + smem[3 * 256 + idx] +
                     smem[5 * 256 + idx] + smem[7 * 256 + idx];
          int b = hd_mb * 16 + quad * 4 + r;
          int s = hd_sb * 16 + row16;
          float std = __expf(0.5f * lv);
          float z = nz[r] * std + mean;
          __hip_bfloat16 zb = __float2bfloat16(z);
          zall[((size_t)b * Tdim + t) * Sdim + s] = zb;  // scan-private: normal store
          unsigned zu = (unsigned)reinterpret_cast<unsigned short&>(zb);
          unsigned up = zu | (__shfl_xor(zu, 1, 64) << 16);  // s-cols {s, s+1}
          unsigned uq = __shfl_xor(up, 2, 64);               // s-cols {s+2, s+3}
          if ((row16 & 3) == 0)
            astore8(AbW + (size_t)b * KG + s, (ull)up | ((ull)uq << 32));
          klw += std * std + mean * mean - 0.5f * lv - 0.5f;  // log(std)=0.5*lv
        }
      }
      __syncthreads();  // w0's z-stores drained before publish
      if (tid == 0)
        __hip_atomic_store(&flags[blockIdx.x], (unsigned)(t + 1),
                           __ATOMIC_RELAXED, __HIP_MEMORY_SCOPE_AGENT);
    }
  }
  // heads w0: one atomic per block for the whole scan
  if (!is_gates && w == 0) {
    #pragma unroll
    for (int off = 32; off > 0; off >>= 1) klw += __shfl_down(klw, off, 64);
    if (lane == 0) atomicAdd(klacc, klw);
  }
}

// ---------------- decoder GEMM1: Hbuf = relu(zall[32768,128] @ Wd1^T + bd1) -> bf16
__global__ __launch_bounds__(256) void dec1_kernel(char* __restrict__ ws,
                                                   const float* __restrict__ bd1) {
  const __hip_bfloat16* zall = (const __hip_bfloat16*)(ws + ZALL_OFF);
  const __hip_bfloat16* Wd1b = (const __hip_bfloat16*)(ws + WD1_OFF);
  __hip_bfloat16* Hbuf = (__hip_bfloat16*)(ws + HB_OFF);
  int tid = threadIdx.x, lane = tid & 63, w = tid >> 6;
  int mb = blockIdx.x, nb = blockIdx.y;
  int row16 = lane & 15, quad = lane >> 4;
  int arow = mb * 64 + w * 16 + row16;
  const __hip_bfloat16* aptr = zall + (size_t)arow * Sdim;
  floatx4 acc[4] = {{0.f,0.f,0.f,0.f},{0.f,0.f,0.f,0.f},{0.f,0.f,0.f,0.f},{0.f,0.f,0.f,0.f}};
  #pragma unroll
  for (int kt = 0; kt < Sdim / 32; kt++) {
    int k0 = kt * 32 + quad * 8;
    short8 a = *(const short8*)(aptr + k0);
    #pragma unroll
    for (int j = 0; j < 4; j++) {
      const __hip_bfloat16* bp = Wd1b + (size_t)(nb * 64 + j * 16 + row16) * Sdim;
      acc[j] = MFMA(a, *(const short8*)(bp + k0), acc[j]);
    }
  }
  #pragma unroll
  for (int j = 0; j < 4; j++) {
    int n = nb * 64 + j * 16 + row16;
    float bias = bd1[n];
    #pragma unroll
    for (int r = 0; r < 4; r++) {
      int rr = mb * 64 + w * 16 + quad * 4 + r;
      float v = fmaxf(acc[j][r] + bias, 0.0f);
      Hbuf[(size_t)rr * DHdim + n] = __float2bfloat16(v);
    }
  }
}

// ---------------- decoder GEMM2: out = Hbuf[32768,1024] @ Wd2^T + bd2 -> f32
__global__ __launch_bounds__(256) void dec2_kernel(char* __restrict__ ws,
                                                   const float* __restrict__ bd2,
                                                   float* __restrict__ out) {
  const __hip_bfloat16* Hbuf = (const __hip_bfloat16*)(ws + HB_OFF);
  const __hip_bfloat16* Wd2b = (const __hip_bfloat16*)(ws + WD2_OFF);
  int tid = threadIdx.x, lane = tid & 63, w = tid >> 6;
  int mb = blockIdx.x, nb = blockIdx.y;
  int row16 = lane & 15, quad = lane >> 4;
  int arow = mb * 64 + w * 16 + row16;
  const __hip_bfloat16* aptr = Hbuf + (size_t)arow * DHdim;
  const __hip_bfloat16* bp[4];
  #pragma unroll
  for (int j = 0; j < 4; j++) bp[j] = Wd2b + (size_t)(nb * 64 + j * 16 + row16) * DHdim;
  floatx4 acc[4] = {{0.f,0.f,0.f,0.f},{0.f,0.f,0.f,0.f},{0.f,0.f,0.f,0.f},{0.f,0.f,0.f,0.f}};
  for (int kt = 0; kt < DHdim / 32; kt++) {
    int k0 = kt * 32 + quad * 8;
    short8 a = *(const short8*)(aptr + k0);
    #pragma unroll
    for (int j = 0; j < 4; j++)
      acc[j] = MFMA(a, *(const short8*)(bp[j] + k0), acc[j]);
  }
  #pragma unroll
  for (int j = 0; j < 4; j++) {
    int n = nb * 64 + j * 16 + row16;
    float bias = bd2[n];
    #pragma unroll
    for (int r = 0; r < 4; r++) {
      int rr = mb * 64 + w * 16 + quad * 4 + r;
      out[(size_t)rr * DIN + n] = acc[j][r] + bias;
    }
  }
}

__global__ void kl_write_kernel(const char* __restrict__ ws, float* __restrict__ out) {
  if (threadIdx.x == 0 && blockIdx.x == 0)
    out[16777216] = *(const float*)(ws + KL_OFF);
}

extern "C" void kernel_launch(void* const* d_in, const int* in_sizes, int n_in,
                              void* d_out, int out_size, void* d_ws, size_t ws_size,
                              hipStream_t stream) {
  const float* x = (const float*)d_in[0];
  const float* noise = (const float*)d_in[1];
  const float* W_ih = (const float*)d_in[2];
  const float* W_hh = (const float*)d_in[3];
  const float* b_ih = (const float*)d_in[4];
  const float* b_hh = (const float*)d_in[5];
  const float* Wm = (const float*)d_in[6];
  const float* bm = (const float*)d_in[7];
  const float* Wv = (const float*)d_in[8];
  const float* bv = (const float*)d_in[9];
  const float* Wd1 = (const float*)d_in[10];
  const float* bd1 = (const float*)d_in[11];
  const float* Wd2 = (const float*)d_in[12];
  const float* bd2 = (const float*)d_in[13];
  char* ws = (char*)d_ws;
  float* out = (float*)d_out;

  long long total_prep = 22692033LL;
  int pblocks = (int)((total_prep + 255) / 256);
  prep_kernel<<<pblocks, 256, 0, stream>>>(x, W_ih, W_hh, Wm, Wv, Wd1, Wd2, ws);
  scan_kernel<<<NBLK, 256, 0, stream>>>(ws, noise, b_ih, b_hh, bm, bv);
  dec1_kernel<<<dim3(512, 16), 256, 0, stream>>>(ws, bd1);
  dec2_kernel<<<dim3(512, 8), 256, 0, stream>>>(ws, bd2, out);
  kl_write_kernel<<<1, 64, 0, stream>>>(ws, out);
}

// Round 9
// 5526.630 us; speedup vs baseline: 1.3798x; 1.3798x over previous
//
#include <hip/hip_runtime.h>
#include <hip/hip_bf16.h>

#define Bdim 128
#define Tdim 256
#define DIN 512
#define Hdim 1024
#define Sdim 128
#define DHdim 1024
#define KG 1152   // S + H (gates GEMM K)
#define KP 1536   // DIN + H (heads GEMM K)
#define NBLK 192  // persistent: 128 gates blocks + 64 heads blocks
#define LDP 1160  // gates LDS A-panel row stride (1152 + 8 pad)

using short8  = __attribute__((ext_vector_type(8))) short;   // 8 bf16 (4 VGPRs)
using floatx4 = __attribute__((ext_vector_type(4))) float;   // MFMA accum
typedef unsigned long long ull;

#define MFMA(a, b, c) __builtin_amdgcn_mfma_f32_16x16x32_bf16((a), (b), (c), 0, 0, 0)

// ---- workspace layout (bytes). Scan-phase staging (xbf/Wg/Wmv) unions with
// Hbuf (decoder intermediate), which is written only after the scan finishes.
#define XBF_OFF   0ull            // 128*256*512 bf16 = 33,554,432
#define WG_OFF    33554432ull     // 4096*1152 bf16 = 9,437,184
#define WMV_OFF   42991616ull     // 256*1536 bf16 = 786,432
#define HB_OFF    0ull            // 32768*1024 bf16 = 67,108,864 (unions scan staging)
#define WD1_OFF   67108864ull     // 1024*128 bf16 = 262,144
#define WD2_OFF   67371008ull     // 512*1024 bf16 = 1,048,576
#define AB_OFF    68419584ull     // 2 x 128*1152 bf16 (ping-pong [z|h]) = 589,824
#define AB_SZ     294912ull
#define ZALL_OFF  69009408ull     // 32768*128 bf16 = 8,388,608
#define KL_OFF    77398016ull     // 1 f32
#define FLG_OFF   77398144ull     // 192 x u32 monotonic per-producer seqno flags

__device__ __forceinline__ float sigf(float v) { return 1.0f / (1.0f + __expf(-v)); }
__device__ __forceinline__ float tanhfast(float v) { return 1.0f - 2.0f / (__expf(2.0f * v) + 1.0f); }

// 16B agent-coherent load: ONE coherent transaction.
// Protocol (vmcnt-accounting safety, round-1 lesson): asm loads only outstanding
// inside a staging burst, drained by VMWAIT0 before ANY compiler memory op.
__device__ __forceinline__ short8 cload16(const __hip_bfloat16* p) {
  short8 r;
  asm volatile("global_load_dwordx4 %0, %1, off sc0 sc1" : "=&v"(r) : "v"(p));
  return r;
}
#define VMWAIT0()                                              \
  do {                                                         \
    asm volatile("s_waitcnt vmcnt(0)" ::: "memory");           \
    __builtin_amdgcn_sched_barrier(0);                         \
  } while (0)
#define SB0() __builtin_amdgcn_sched_barrier(0)

__device__ __forceinline__ void astore8(__hip_bfloat16* p, ull v) {
  __hip_atomic_store((ull*)(void*)p, v, __ATOMIC_RELAXED, __HIP_MEMORY_SCOPE_AGENT);
}

// Wave0-only polling + s_sleep(8) backoff (round-3 proven); callers release the
// other waves with __syncthreads().
__device__ __forceinline__ void waitflags(unsigned* flags, int base, int mask,
                                          unsigned target, int lane) {
  unsigned* p = flags + base + (lane & mask);
  while (!__all((int)(__hip_atomic_load(p, __ATOMIC_RELAXED, __HIP_MEMORY_SCOPE_AGENT) >= target))) {
    __builtin_amdgcn_s_sleep(8);
  }
}

// ---------------- prep: fp32->bf16 conversions, weight packing, state zeroing
__global__ __launch_bounds__(256) void prep_kernel(
    const float* __restrict__ x, const float* __restrict__ W_ih,
    const float* __restrict__ W_hh, const float* __restrict__ Wm,
    const float* __restrict__ Wv, const float* __restrict__ Wd1,
    const float* __restrict__ Wd2, char* __restrict__ ws) {
  long long i = (long long)blockIdx.x * 256 + threadIdx.x;
  if (i < 16777216LL) {  // x -> xbf  [B][T][DIN]
    ((__hip_bfloat16*)(ws + XBF_OFF))[i] = __float2bfloat16(x[i]);
    return;
  }
  i -= 16777216LL;
  if (i < 4718592LL) {  // Wg[4096][1152] = [W_ih | W_hh]
    int j = (int)(i / KG), k = (int)(i % KG);
    float v = (k < Sdim) ? W_ih[j * Sdim + k] : W_hh[(long long)j * Hdim + (k - Sdim)];
    ((__hip_bfloat16*)(ws + WG_OFF))[i] = __float2bfloat16(v);
    return;
  }
  i -= 4718592LL;
  if (i < 393216LL) {  // Wmv[256][1536] = [Wm ; Wv]
    int r = (int)(i / KP), k = (int)(i % KP);
    float v = (r < Sdim) ? Wm[r * KP + k] : Wv[(r - Sdim) * KP + k];
    ((__hip_bfloat16*)(ws + WMV_OFF))[i] = __float2bfloat16(v);
    return;
  }
  i -= 393216LL;
  if (i < 131072LL) { ((__hip_bfloat16*)(ws + WD1_OFF))[i] = __float2bfloat16(Wd1[i]); return; }
  i -= 131072LL;
  if (i < 524288LL) { ((__hip_bfloat16*)(ws + WD2_OFF))[i] = __float2bfloat16(Wd2[i]); return; }
  i -= 524288LL;
  if (i < 147456LL) { ((__hip_bfloat16*)(ws + AB_OFF))[i] = __float2bfloat16(0.0f); return; }  // [z0|h0]=0
  i -= 147456LL;
  if (i == 0) { *((float*)(ws + KL_OFF)) = 0.0f; return; }
  i -= 1;
  if (i < 192LL) { ((unsigned*)(ws + FLG_OFF))[i] = 0u; return; }
}

// ---------------- persistent scan: whole T=256 recurrence in ONE kernel.
// Round-9: gates block tile 64x64 -> 16x256 with LDS A-panel sharing; per-wave
// GEMM shape is EXACTLY round-3's proven form (acc[4], 4 weight streams/kt,
// 144 MFMA) with A from ds_read instead of global. A coherent traffic
// 18.9 -> 4.7 MB/step. Gates block b<128: mgrp=b>>4 (rows mgrp*16..+16),
// ns=b&15 (hcols ns*64..+64, x4 gates). Heads (64 blocks) unchanged from r3.
// Flags: [0..127] gates (cohort = 16 blocks sharing mgrp), [128..191] heads.
__global__ __launch_bounds__(256, 1) void scan_kernel(
    char* __restrict__ ws, const float* __restrict__ noise,
    const float* __restrict__ b_ih, const float* __restrict__ b_hh,
    const float* __restrict__ bm, const float* __restrict__ bv) {
  const __hip_bfloat16* WG = (const __hip_bfloat16*)(ws + WG_OFF);
  const __hip_bfloat16* WMV = (const __hip_bfloat16*)(ws + WMV_OFF);
  const __hip_bfloat16* xbf = (const __hip_bfloat16*)(ws + XBF_OFF);
  __hip_bfloat16* zall = (__hip_bfloat16*)(ws + ZALL_OFF);
  float* klacc = (float*)(ws + KL_OFF);
  unsigned* flags = (unsigned*)(ws + FLG_OFF);

  // gates: bf16 A-panel [16][LDP] = 37120 B. heads: f32 reduce smem (8 KB). union.
  __shared__ __align__(16) char ldsraw[16 * LDP * 2];
  __hip_bfloat16* lds = (__hip_bfloat16*)ldsraw;
  float* smem = (float*)ldsraw;

  const int tid = threadIdx.x;
  const int lane = tid & 63;
  const int w = tid >> 6;
  const int row16 = lane & 15;
  const int quad = lane >> 4;
  const int bid = blockIdx.x;
  const bool is_gates = (bid < 128);

  // ---- gates-role setup
  const __hip_bfloat16* gb_bp[4];
  float biasv[4];
  int mgrp = 0, ns = 0, rowbase = 0;
  float creg[4] = {0.f, 0.f, 0.f, 0.f};
  // ---- heads-role setup
  const __hip_bfloat16* hd_bpm = nullptr;
  const __hip_bfloat16* hd_bpv = nullptr;
  int hd_mb = 0, hd_sb = 0, hd_nx = 0, hd_kbase = 0;
  float hbm = 0.f, hbv = 0.f;
  float klw = 0.f;  // heads w0: KL accumulated over all t

  if (is_gates) {
    mgrp = bid >> 4;
    ns = bid & 15;
    rowbase = mgrp * 16;
    #pragma unroll
    for (int j = 0; j < 4; j++) {
      int idx = j * Hdim + ns * 64 + w * 16 + row16;  // gate j, hcol slice (per-wave)
      gb_bp[j] = WG + (size_t)idx * KG;
      biasv[j] = b_ih[idx] + b_hh[idx];
    }
  } else {
    int hb = bid - 128;
    hd_mb = hb >> 3;
    hd_sb = hb & 7;
    int s = hd_sb * 16 + row16;
    hd_bpm = WMV + (size_t)s * KP;
    hd_bpv = WMV + (size_t)(128 + s) * KP;
    hbm = bm[s];
    hbv = bv[s];
    hd_kbase = w * 384;
    hd_nx = (hd_kbase < DIN) ? ((DIN - hd_kbase) >> 5) : 0;  // 12,4,0,0
    if (hd_nx > 12) hd_nx = 12;
  }

  for (int t = 0; t < Tdim; t++) {
    const int par = t & 1;
    const __hip_bfloat16* Ab = (const __hip_bfloat16*)(ws + AB_OFF + (ull)par * AB_SZ);
    __hip_bfloat16* AbW = (__hip_bfloat16*)(ws + AB_OFF + (ull)(par ^ 1) * AB_SZ);

    if (is_gates) {
      floatx4 acc[4];
      #pragma unroll
      for (int j = 0; j < 4; j++)
        acc[j] = (floatx4){biasv[j], biasv[j], biasv[j], biasv[j]};

      // --- h-wait (cohort = my 16-row panel's producers at t-1; also WAR guard)
      if (w == 0) waitflags(flags, mgrp * 16, 15, (unsigned)t, lane);
      __syncthreads();  // release: data ordered after wave0's flag observation
      // --- stage h-panel into LDS: 16 rows x 1024 cols = 2048 16B-segs, 8/thread
      {
        short8 sreg[8];
        #pragma unroll
        for (int i = 0; i < 8; i++) {
          int s = tid + i * 256;
          sreg[i] = cload16(Ab + (size_t)(rowbase + (s >> 7)) * KG + Sdim + (s & 127) * 8);
        }
        VMWAIT0();  // drain asm loads before compiler ds_writes
        #pragma unroll
        for (int i = 0; i < 8; i++) {
          int s = tid + i * 256;
          *(short8*)&lds[(s >> 7) * LDP + Sdim + (s & 127) * 8] = sreg[i];
        }
      }
      __syncthreads();  // panel visible to all waves
      // --- h-region MFMA from LDS (r3 per-wave shape; SB0 every 4 kts caps window)
      #pragma unroll
      for (int c = 0; c < 8; c++) {
        #pragma unroll
        for (int i = 0; i < 4; i++) {
          const int k0 = Sdim + (c * 4 + i) * 32 + quad * 8;
          short8 a = *(const short8*)&lds[row16 * LDP + k0];
          #pragma unroll
          for (int j = 0; j < 4; j++)
            acc[j] = MFMA(a, *(const short8*)(gb_bp[j] + k0), acc[j]);
        }
        SB0();
      }
      // --- z-wait (heads covering my rows, t-1) + stage z: 256 segs, 1/thread
      if (w == 0) waitflags(flags, 128 + mgrp * 8, 7, (unsigned)t, lane);
      __syncthreads();
      {
        short8 zs = cload16(Ab + (size_t)(rowbase + (tid >> 4)) * KG + (tid & 15) * 8);
        VMWAIT0();
        *(short8*)&lds[(tid >> 4) * LDP + (tid & 15) * 8] = zs;
      }
      __syncthreads();
      #pragma unroll
      for (int kt = 0; kt < 4; kt++) {
        const int k0 = kt * 32 + quad * 8;
        short8 a = *(const short8*)&lds[row16 * LDP + k0];
        #pragma unroll
        for (int j = 0; j < 4; j++)
          acc[j] = MFMA(a, *(const short8*)(gb_bp[j] + k0), acc[j]);
      }
      SB0();
      // --- LSTM cell, lane-local: acc[j][r] = gate j at (row quad*4+r, hcol row16)
      int hc = ns * 64 + w * 16 + row16;
      #pragma unroll
      for (int r = 0; r < 4; r++) {
        float cn = sigf(acc[1][r]) * creg[r] + sigf(acc[0][r]) * tanhfast(acc[2][r]);
        creg[r] = cn;
        float hn = sigf(acc[3][r]) * tanhfast(cn);
        __hip_bfloat16 hbf = __float2bfloat16(hn);
        unsigned hu = (unsigned)reinterpret_cast<unsigned short&>(hbf);
        unsigned up = hu | (__shfl_xor(hu, 1, 64) << 16);  // hcols {hc, hc+1}
        unsigned uq = __shfl_xor(up, 2, 64);               // hcols {hc+2, hc+3}
        if ((row16 & 3) == 0) {
          int grow = rowbase + quad * 4 + r;
          astore8(AbW + (size_t)grow * KG + Sdim + hc, (ull)up | ((ull)uq << 32));
        }
      }
      __syncthreads();  // drain all waves' h-stores (vmcnt 0) before publishing
      if (tid == 0)
        __hip_atomic_store(&flags[bid], (unsigned)(t + 1),
                           __ATOMIC_RELAXED, __HIP_MEMORY_SCOPE_AGENT);
    } else {
      // --- noise prefetch (static input): issue before any wait, used in epilogue
      float nz[4];
      if (w == 0) {
        #pragma unroll
        for (int r = 0; r < 4; r++) {
          int b = hd_mb * 16 + quad * 4 + r;
          int s = hd_sb * 16 + row16;
          nz[r] = noise[((size_t)b * Tdim + t) * Sdim + s];
        }
      }
      // --- x-region first (static input, no wait)
      const __hip_bfloat16* axp = xbf + ((size_t)(hd_mb * 16 + row16) * Tdim + t) * DIN;
      const __hip_bfloat16* ahp = AbW + (size_t)(hd_mb * 16 + row16) * KG + Sdim;
      floatx4 am, av;
      if (w == 0) { am = (floatx4){hbm, hbm, hbm, hbm}; av = (floatx4){hbv, hbv, hbv, hbv}; }
      else        { am = (floatx4){0.f, 0.f, 0.f, 0.f}; av = (floatx4){0.f, 0.f, 0.f, 0.f}; }
      #pragma unroll
      for (int kt = 0; kt < 12; kt++) {
        if (kt < hd_nx) {
          int k0 = hd_kbase + kt * 32 + quad * 8;
          short8 a = *(const short8*)(axp + k0);
          am = MFMA(a, *(const short8*)(hd_bpm + k0), am);
          av = MFMA(a, *(const short8*)(hd_bpv + k0), av);
        }
      }
      // --- h-region: wait for the 16 gates blocks covering my rows (step t)
      if (w == 0) waitflags(flags, hd_mb * 16, 15, (unsigned)(t + 1), lane);
      __syncthreads();
      short8 hreg[12];
      #pragma unroll
      for (int kt = 0; kt < 12; kt++) {
        if (kt >= hd_nx)
          hreg[kt] = cload16(ahp + hd_kbase + kt * 32 + quad * 8 - DIN);
      }
      VMWAIT0();
      #pragma unroll
      for (int kt = 0; kt < 12; kt++) {
        if (kt >= hd_nx) {
          int k0 = hd_kbase + kt * 32 + quad * 8;
          am = MFMA(hreg[kt], *(const short8*)(hd_bpm + k0), am);
          av = MFMA(hreg[kt], *(const short8*)(hd_bpv + k0), av);
        }
      }
      SB0();
      // --- cross-wave K reduction through LDS
      #pragma unroll
      for (int r = 0; r < 4; r++) {
        smem[(w * 2 + 0) * 256 + lane * 4 + r] = am[r];
        smem[(w * 2 + 1) * 256 + lane * 4 + r] = av[r];
      }
      __syncthreads();
      if (w == 0) {
        #pragma unroll
        for (int r = 0; r < 4; r++) {
          int idx = lane * 4 + r;
          float mean = smem[0 * 256 + idx] + smem[2 * 256 + idx] +
                       smem[4 * 256 + idx] + smem[6 * 256 + idx];
          float lv = smem[1 * 256 + idx] + smem[3 * 256 + idx] +
                     smem[5 * 256 + idx] + smem[7 * 256 + idx];
          int b = hd_mb * 16 + quad * 4 + r;
          int s = hd_sb * 16 + row16;
          float std = __expf(0.5f * lv);
          float z = nz[r] * std + mean;
          __hip_bfloat16 zb = __float2bfloat16(z);
          zall[((size_t)b * Tdim + t) * Sdim + s] = zb;  // scan-private: normal store
          unsigned zu = (unsigned)reinterpret_cast<unsigned short&>(zb);
          unsigned up = zu | (__shfl_xor(zu, 1, 64) << 16);  // s-cols {s, s+1}
          unsigned uq = __shfl_xor(up, 2, 64);               // s-cols {s+2, s+3}
          if ((row16 & 3) == 0)
            astore8(AbW + (size_t)b * KG + s, (ull)up | ((ull)uq << 32));
          klw += std * std + mean * mean - 0.5f * lv - 0.5f;  // log(std)=0.5*lv
        }
      }
      __syncthreads();  // w0's z-stores drained before publish
      if (tid == 0)
        __hip_atomic_store(&flags[bid], (unsigned)(t + 1),
                           __ATOMIC_RELAXED, __HIP_MEMORY_SCOPE_AGENT);
    }
  }
  // heads w0: one atomic per block for the whole scan
  if (!is_gates && w == 0) {
    #pragma unroll
    for (int off = 32; off > 0; off >>= 1) klw += __shfl_down(klw, off, 64);
    if (lane == 0) atomicAdd(klacc, klw);
  }
}

// ---------------- decoder GEMM1: Hbuf = relu(zall[32768,128] @ Wd1^T + bd1) -> bf16
__global__ __launch_bounds__(256) void dec1_kernel(char* __restrict__ ws,
                                                   const float* __restrict__ bd1) {
  const __hip_bfloat16* zall = (const __hip_bfloat16*)(ws + ZALL_OFF);
  const __hip_bfloat16* Wd1b = (const __hip_bfloat16*)(ws + WD1_OFF);
  __hip_bfloat16* Hbuf = (__hip_bfloat16*)(ws + HB_OFF);
  int tid = threadIdx.x, lane = tid & 63, w = tid >> 6;
  int mb = blockIdx.x, nb = blockIdx.y;
  int row16 = lane & 15, quad = lane >> 4;
  int arow = mb * 64 + w * 16 + row16;
  const __hip_bfloat16* aptr = zall + (size_t)arow * Sdim;
  floatx4 acc[4] = {{0.f,0.f,0.f,0.f},{0.f,0.f,0.f,0.f},{0.f,0.f,0.f,0.f},{0.f,0.f,0.f,0.f}};
  #pragma unroll
  for (int kt = 0; kt < Sdim / 32; kt++) {
    int k0 = kt * 32 + quad * 8;
    short8 a = *(const short8*)(aptr + k0);
    #pragma unroll
    for (int j = 0; j < 4; j++) {
      const __hip_bfloat16* bp = Wd1b + (size_t)(nb * 64 + j * 16 + row16) * Sdim;
      acc[j] = MFMA(a, *(const short8*)(bp + k0), acc[j]);
    }
  }
  #pragma unroll
  for (int j = 0; j < 4; j++) {
    int n = nb * 64 + j * 16 + row16;
    float bias = bd1[n];
    #pragma unroll
    for (int r = 0; r < 4; r++) {
      int rr = mb * 64 + w * 16 + quad * 4 + r;
      float v = fmaxf(acc[j][r] + bias, 0.0f);
      Hbuf[(size_t)rr * DHdim + n] = __float2bfloat16(v);
    }
  }
}

// ---------------- decoder GEMM2: out = Hbuf[32768,1024] @ Wd2^T + bd2 -> f32
__global__ __launch_bounds__(256) void dec2_kernel(char* __restrict__ ws,
                                                   const float* __restrict__ bd2,
                                                   float* __restrict__ out) {
  const __hip_bfloat16* Hbuf = (const __hip_bfloat16*)(ws + HB_OFF);
  const __hip_bfloat16* Wd2b = (const __hip_bfloat16*)(ws + WD2_OFF);
  int tid = threadIdx.x, lane = tid & 63, w = tid >> 6;
  int mb = blockIdx.x, nb = blockIdx.y;
  int row16 = lane & 15, quad = lane >> 4;
  int arow = mb * 64 + w * 16 + row16;
  const __hip_bfloat16* aptr = Hbuf + (size_t)arow * DHdim;
  const __hip_bfloat16* bp[4];
  #pragma unroll
  for (int j = 0; j < 4; j++) bp[j] = Wd2b + (size_t)(nb * 64 + j * 16 + row16) * DHdim;
  floatx4 acc[4] = {{0.f,0.f,0.f,0.f},{0.f,0.f,0.f,0.f},{0.f,0.f,0.f,0.f},{0.f,0.f,0.f,0.f}};
  for (int kt = 0; kt < DHdim / 32; kt++) {
    int k0 = kt * 32 + quad * 8;
    short8 a = *(const short8*)(aptr + k0);
    #pragma unroll
    for (int j = 0; j < 4; j++)
      acc[j] = MFMA(a, *(const short8*)(bp[j] + k0), acc[j]);
  }
  #pragma unroll
  for (int j = 0; j < 4; j++) {
    int n = nb * 64 + j * 16 + row16;
    float bias = bd2[n];
    #pragma unroll
    for (int r = 0; r < 4; r++) {
      int rr = mb * 64 + w * 16 + quad * 4 + r;
      out[(size_t)rr * DIN + n] = acc[j][r] + bias;
    }
  }
}

__global__ void kl_write_kernel(const char* __restrict__ ws, float* __restrict__ out) {
  if (threadIdx.x == 0 && blockIdx.x == 0)
    out[16777216] = *(const float*)(ws + KL_OFF);
}

extern "C" void kernel_launch(void* const* d_in, const int* in_sizes, int n_in,
                              void* d_out, int out_size, void* d_ws, size_t ws_size,
                              hipStream_t stream) {
  const float* x = (const float*)d_in[0];
  const float* noise = (const float*)d_in[1];
  const float* W_ih = (const float*)d_in[2];
  const float* W_hh = (const float*)d_in[3];
  const float* b_ih = (const float*)d_in[4];
  const float* b_hh = (const float*)d_in[5];
  const float* Wm = (const float*)d_in[6];
  const float* bm = (const float*)d_in[7];
  const float* Wv = (const float*)d_in[8];
  const float* bv = (const float*)d_in[9];
  const float* Wd1 = (const float*)d_in[10];
  const float* bd1 = (const float*)d_in[11];
  const float* Wd2 = (const float*)d_in[12];
  const float* bd2 = (const float*)d_in[13];
  char* ws = (char*)d_ws;
  float* out = (float*)d_out;

  long long total_prep = 22692033LL;
  int pblocks = (int)((total_prep + 255) / 256);
  prep_kernel<<<pblocks, 256, 0, stream>>>(x, W_ih, W_hh, Wm, Wv, Wd1, Wd2, ws);
  scan_kernel<<<NBLK, 256, 0, stream>>>(ws, noise, b_ih, b_hh, bm, bv);
  dec1_kernel<<<dim3(512, 16), 256, 0, stream>>>(ws, bd1);
  dec2_kernel<<<dim3(512, 8), 256, 0, stream>>>(ws, bd2, out);
  kl_write_kernel<<<1, 64, 0, stream>>>(ws, out);
}